// Round 5
// baseline (258.918 us; speedup 1.0000x reference)
//
#include <hip/hip_runtime.h>
#include <hip/hip_bf16.h>

#define Bb 256
#define Ss 2048
#define Tt 48

static constexpr float C_SHIFT = 4.875f;  // ~ln(48)+1: per-step growth ~= 1

typedef float f4   __attribute__((ext_vector_type(4)));
typedef short s4h  __attribute__((ext_vector_type(4)));
typedef __bf16 bf16x8 __attribute__((ext_vector_type(8)));

union U32x4 { unsigned u[4]; bf16x8 v; };
union U32x2 { unsigned u[2]; s4h v; };

__device__ __forceinline__ unsigned pk_trunc(float lo, float hi) {
    unsigned a = __builtin_bit_cast(unsigned, lo);
    unsigned b = __builtin_bit_cast(unsigned, hi);
#if __has_builtin(__builtin_amdgcn_perm)
    return __builtin_amdgcn_perm(b, a, 0x07060302u);
#else
    return (b & 0xFFFF0000u) | (a >> 16);
#endif
}
__device__ __forceinline__ unsigned pk_rne(float lo, float hi) {
    __hip_bfloat162 h = __float22bfloat162_rn(make_float2(lo, hi));
    union { __hip_bfloat16 b[2]; unsigned u; } t;
    t.b[0] = h.x; t.b[1] = h.y;
    return t.u;
}
__device__ __forceinline__ float bfu(unsigned u) { return __builtin_bit_cast(float, u); }

// k-slot bijection for the x32 operands: slot (g,j) holds k = sig(g,j).
__device__ __forceinline__ int sig32(int g, int j) {
    return 16 * (j >> 2) + 4 * g + (j & 3);
}

#define MFMA32(a,b,c) __builtin_amdgcn_mfma_f32_16x16x32_bf16(a, b, c, 0, 0, 0)
#define MFMA16(a,b,c) __builtin_amdgcn_mfma_f32_16x16x16bf16_1k(a, b, c, 0, 0, 0)

// ---------------------------------------------------------------------------
// One scan step (round-0 proven scalar form): per n-tile, D = A32*B32 (rows
// 0..31) + A16*B16 (rows 32..47), rowscale by e, repack.
// ---------------------------------------------------------------------------
__device__ __forceinline__ void scan_step(const bf16x8 (&A32)[3], const s4h (&A16)[3],
                                          bf16x8 (&B32)[3], s4h (&B16)[3],
                                          const float* __restrict__ eb)
{
    f4 e0 = *(const f4*)(eb);          // e[4g + 0..3]      (rows of m-tile 0)
    f4 e1 = *(const f4*)(eb + 16);     // e[16 + 4g + 0..3] (m-tile 1)
    f4 e2 = *(const f4*)(eb + 32);     // e[32 + 4g + 0..3] (m-tile 2)
    const f4 z = {0.f, 0.f, 0.f, 0.f};
#pragma unroll
    for (int nt = 0; nt < 3; ++nt) {
        f4 c0v = MFMA32(A32[0], B32[nt], z);
        f4 c1v = MFMA32(A32[1], B32[nt], z);
        f4 c2v = MFMA32(A32[2], B32[nt], z);
        c0v = MFMA16(A16[0], B16[nt], c0v);
        c1v = MFMA16(A16[1], B16[nt], c1v);
        c2v = MFMA16(A16[2], B16[nt], c2v);
        U32x4 nb;
        nb.u[0] = pk_trunc(c0v[0] * e0[0], c0v[1] * e0[1]);
        nb.u[1] = pk_trunc(c0v[2] * e0[2], c0v[3] * e0[3]);
        nb.u[2] = pk_trunc(c1v[0] * e1[0], c1v[1] * e1[1]);
        nb.u[3] = pk_trunc(c1v[2] * e1[2], c1v[3] * e1[3]);
        B32[nt] = nb.v;
        U32x2 nc;
        nc.u[0] = pk_trunc(c2v[0] * e2[0], c2v[1] * e2[1]);
        nc.u[1] = pk_trunc(c2v[2] * e2[2], c2v[3] * e2[3]);
        B16[nt] = nc.v;
    }
}

// ---------------------------------------------------------------------------
// Phase 1: one wave per (batch, chunk): 48x48 transfer-matrix product in regs.
// Templated on chunk count: NC=24 -> 1536 blocks = 6 blocks/CU = 6 waves/SIMD
// (occupancy-doubling vs round-0's NC=12 / 3 waves/SIMD). Body identical to
// the round-0-proven kernel.
// ---------------------------------------------------------------------------
template<int NC, int CL, int WPC>
__global__ __launch_bounds__(256, WPC)
void crf_scan(const float* __restrict__ em, const float* __restrict__ trn,
              float* __restrict__ pws, float* __restrict__ outz)
{
    __shared__ float lex[4][16 * Tt];          // per-wave 16-step exp(em) buffer
    const int tid = threadIdx.x, wv = tid >> 6, l = tid & 63;
    const int c0 = l & 15, g = l >> 4;
    const int wid = blockIdx.x * 4 + wv;
    const int b = wid / NC, ck = wid % NC;
    if (blockIdx.x == 0 && tid == 0) outz[0] = 0.0f;   // zero d_out for finish

    // A-frags: A32[mt] slot (g,j) = exp(trn[sig32(g,j)][16mt+c0])
    bf16x8 A32[3]; s4h A16[3];
#pragma unroll
    for (int mt = 0; mt < 3; ++mt) {
        float v[8];
#pragma unroll
        for (int j = 0; j < 8; ++j)
            v[j] = __expf(trn[sig32(g, j) * Tt + 16 * mt + c0]);
        U32x4 a;
        a.u[0] = pk_rne(v[0], v[1]); a.u[1] = pk_rne(v[2], v[3]);
        a.u[2] = pk_rne(v[4], v[5]); a.u[3] = pk_rne(v[6], v[7]);
        A32[mt] = a.v;
        float w0 = __expf(trn[(32 + 4 * g + 0) * Tt + 16 * mt + c0]);
        float w1 = __expf(trn[(32 + 4 * g + 1) * Tt + 16 * mt + c0]);
        float w2 = __expf(trn[(32 + 4 * g + 2) * Tt + 16 * mt + c0]);
        float w3 = __expf(trn[(32 + 4 * g + 3) * Tt + 16 * mt + c0]);
        U32x2 c;
        c.u[0] = pk_rne(w0, w1); c.u[1] = pk_rne(w2, w3);
        A16[mt] = c.v;
    }

    // State init = identity
    bf16x8 B32[3]; s4h B16[3];
#pragma unroll
    for (int nt = 0; nt < 3; ++nt) {
        U32x4 bi;
#pragma unroll
        for (int q = 0; q < 4; ++q) {
            unsigned lo = (sig32(g, 2 * q)     == 16 * nt + c0) ? 0x3F80u : 0u;
            unsigned hi = (sig32(g, 2 * q + 1) == 16 * nt + c0) ? 0x3F80u : 0u;
            bi.u[q] = lo | (hi << 16);
        }
        B32[nt] = bi.v;
        U32x2 ci;
#pragma unroll
        for (int q = 0; q < 2; ++q) {
            unsigned lo = (nt == 2 && 4 * g + 2 * q     == c0) ? 0x3F80u : 0u;
            unsigned hi = (nt == 2 && 4 * g + 2 * q + 1 == c0) ? 0x3F80u : 0u;
            ci.u[q] = lo | (hi << 16);
        }
        B16[nt] = ci.v;
    }

    const int total = (ck == NC - 1) ? (Ss - 1 - ck * CL) : CL;
    const int s0 = ck * CL + 1;
    const float* emb = em + (size_t)b * (Ss * Tt);
    float* lw = &lex[wv][0];
    const float* lexg = lw + g * 4;
    const long lim = (long)Ss * Tt - 4;

    // prefetch sub 0 (early-issued global loads, consumed at loop top)
    f4 r[3];
#pragma unroll
    for (int i = 0; i < 3; ++i) {
        long o = (long)s0 * Tt + l * 4 + i * 256;
        if (o > lim) o = lim;
        r[i] = *(const f4*)(emb + o);
    }

    const int nsub = (total + 15) >> 4;
    for (int sub = 0; sub < nsub; ++sub) {
#pragma unroll
        for (int i = 0; i < 3; ++i)
#pragma unroll
            for (int j = 0; j < 4; ++j) r[i][j] = __expf(r[i][j] - C_SHIFT);
#pragma unroll
        for (int i = 0; i < 3; ++i) *(f4*)(lw + l * 4 + i * 256) = r[i];

        if (sub + 1 < nsub) {        // issue next sub's loads before compute
#pragma unroll
            for (int i = 0; i < 3; ++i) {
                long o = (long)(s0 + (sub + 1) * 16) * Tt + l * 4 + i * 256;
                if (o > lim) o = lim;
                r[i] = *(const f4*)(emb + o);
            }
        }

        int nsteps = total - sub * 16;
        if (nsteps >= 16) {
#pragma unroll
            for (int u = 0; u < 16; ++u)
                scan_step(A32, A16, B32, B16, lexg + u * Tt);
        } else {
            for (int u = 0; u < nsteps; ++u)
                scan_step(A32, A16, B32, B16, lexg + u * Tt);
        }
    }

    // store 18 u32/lane, coalesced
    unsigned* pw = (unsigned*)pws + (size_t)wid * 1152 + l;
#pragma unroll
    for (int nt = 0; nt < 3; ++nt) {
        U32x4 a; a.v = B32[nt];
        U32x2 c; c.v = B16[nt];
        pw[(nt * 6 + 0) * 64] = a.u[0];
        pw[(nt * 6 + 1) * 64] = a.u[1];
        pw[(nt * 6 + 2) * 64] = a.u[2];
        pw[(nt * 6 + 3) * 64] = a.u[3];
        pw[(nt * 6 + 4) * 64] = c.u[0];
        pw[(nt * 6 + 5) * 64] = c.u[1];
    }
}

// ---------------------------------------------------------------------------
// Phase 2 + gold, merged: one block per batch; wave 0 chains the NC chunk
// matrices with renorm, combines with gold. (Round-0 proven structure.)
// ---------------------------------------------------------------------------
template<int NC>
__global__ __launch_bounds__(256)
void crf_finish(const float* __restrict__ em, const int* __restrict__ tags,
                const int* __restrict__ mask, const float* __restrict__ trn,
                const float* __restrict__ stt, const float* __restrict__ ent,
                const float* __restrict__ pws, float* __restrict__ out)
{
    __shared__ float red[256];
    __shared__ float alpha[Tt];
    const int b = blockIdx.x, t = threadIdx.x;

    // gold partial
    const int* tg = tags + (size_t)b * Ss;
    float local = 0.0f;
    for (int s = t; s < Ss; s += 256) {
        if (s > 0) {
            int pv = tg[s - 1], cu = tg[s];
            float mf = (float)mask[(size_t)b * Ss + s];
            local += (trn[pv * Tt + cu] + em[((size_t)b * Ss + s) * Tt + cu]) * mf;
        }
    }
    if (t == 0) {
        int t0 = tg[0];
        local += stt[t0] + em[(size_t)b * Ss * Tt + t0];
        local += ent[tg[Ss - 1]];
    }
    red[t] = local;
    __syncthreads();
    if (t < 128) red[t] += red[t + 128];
    __syncthreads();

    if (t < 64) {
        const int l = t, c0 = l & 15, g = l >> 4;
        float gsum = red[l] + red[l + 64];
#pragma unroll
        for (int m = 32; m >= 1; m >>= 1) gsum += __shfl_xor(gsum, m);

        if (l < Tt) alpha[l] = __expf(stt[l] + em[(size_t)b * Ss * Tt + l] - C_SHIFT);

        float acc = 0.0f;
        const unsigned* pw = (const unsigned*)pws + (size_t)b * NC * 1152 + l;
        for (int ck = 0; ck < NC; ++ck) {
            float y[12];
#pragma unroll
            for (int i = 0; i < 12; ++i) y[i] = 0.0f;
#pragma unroll
            for (int nt = 0; nt < 3; ++nt) {
                float av = alpha[16 * nt + c0];
                unsigned w[6];
#pragma unroll
                for (int q = 0; q < 6; ++q) w[q] = pw[(size_t)ck * 1152 + (nt * 6 + q) * 64];
#pragma unroll
                for (int q = 0; q < 6; ++q) {
                    y[2 * q]     += bfu(w[q] << 16)         * av;
                    y[2 * q + 1] += bfu(w[q] & 0xFFFF0000u) * av;
                }
            }
#pragma unroll
            for (int m = 1; m <= 8; m <<= 1)
#pragma unroll
                for (int i = 0; i < 12; ++i) y[i] += __shfl_xor(y[i], m);
            float mx = y[0];
#pragma unroll
            for (int i = 1; i < 12; ++i) mx = fmaxf(mx, y[i]);
            mx = fmaxf(mx, __shfl_xor(mx, 16));
            mx = fmaxf(mx, __shfl_xor(mx, 32));
            acc += __logf(mx);
            float rm = 1.0f / mx;
            if (c0 == 0) {
#pragma unroll
                for (int tt = 0; tt < 3; ++tt)
#pragma unroll
                    for (int rr = 0; rr < 4; ++rr)
                        alpha[16 * tt + 4 * g + rr] = y[4 * tt + rr] * rm;
            }
        }
        // fwd = log(sum alpha * exp(ent)) + acc + S*C
        float part = (l < Tt) ? alpha[l] * __expf(ent[l]) : 0.0f;
#pragma unroll
        for (int m = 32; m >= 1; m >>= 1) part += __shfl_xor(part, m);
        if (t == 0) {
            float fwd = __logf(part) + acc + (float)Ss * C_SHIFT;
            atomicAdd(out, (fwd - gsum) * (1.0f / 256.0f));
        }
    }
}

// ---------------------------------------------------------------------------
extern "C" void kernel_launch(void* const* d_in, const int* in_sizes, int n_in,
                              void* d_out, int out_size, void* d_ws, size_t ws_size,
                              hipStream_t stream)
{
    const float* em  = (const float*)d_in[0];
    const int* tags  = (const int*)d_in[1];
    const int* mask  = (const int*)d_in[2];
    const float* trn = (const float*)d_in[3];
    const float* stt = (const float*)d_in[4];
    const float* ent = (const float*)d_in[5];
    float* out = (float*)d_out;
    float* pws = (float*)d_ws;

    // NC=24: 6144 waves x 1152 u32 = 28.3 MB workspace; 1536 blocks = 6/CU.
    // Falls back to the round-0-proven NC=12 config if workspace is small.
    constexpr size_t WS24 = (size_t)Bb * 24 * 1152 * 4;
    if (ws_size >= WS24) {
        crf_scan<24, 86, 6><<<Bb * 24 / 4, 256, 0, stream>>>(em, trn, pws, out);
        crf_finish<24><<<Bb, 256, 0, stream>>>(em, tags, mask, trn, stt, ent, pws, out);
    } else {
        crf_scan<12, 171, 3><<<Bb * 12 / 4, 256, 0, stream>>>(em, trn, pws, out);
        crf_finish<12><<<Bb, 256, 0, stream>>>(em, tags, mask, trn, stt, ent, pws, out);
    }
}

// Round 6
// 249.093 us; speedup vs baseline: 1.0394x; 1.0394x over previous
//
#include <hip/hip_runtime.h>
#include <hip/hip_bf16.h>

#define Bb 256
#define Ss 2048
#define Tt 48
#define NCK 12           // chunks per batch (pws = 14.16 MB, proven size)
#define CLEN 171         // steps per chunk (last chunk: 166)

static constexpr float C_SHIFT = 4.875f;  // ~ln(48)+1: per-step growth ~= 1

typedef float f4   __attribute__((ext_vector_type(4)));
typedef short s4h  __attribute__((ext_vector_type(4)));
typedef __bf16 bf16x8 __attribute__((ext_vector_type(8)));

union U32x4 { unsigned u[4]; bf16x8 v; };
union U32x2 { unsigned u[2]; s4h v; };

__device__ __forceinline__ unsigned pk_trunc(float lo, float hi) {
    unsigned a = __builtin_bit_cast(unsigned, lo);
    unsigned b = __builtin_bit_cast(unsigned, hi);
#if __has_builtin(__builtin_amdgcn_perm)
    return __builtin_amdgcn_perm(b, a, 0x07060302u);
#else
    return (b & 0xFFFF0000u) | (a >> 16);
#endif
}
__device__ __forceinline__ unsigned pk_rne(float lo, float hi) {
    __hip_bfloat162 h = __float22bfloat162_rn(make_float2(lo, hi));
    union { __hip_bfloat16 b[2]; unsigned u; } t;
    t.b[0] = h.x; t.b[1] = h.y;
    return t.u;
}
__device__ __forceinline__ float bfu(unsigned u) { return __builtin_bit_cast(float, u); }

// k-slot bijection for the x32 operands: slot (g,j) holds k = sig(g,j).
__device__ __forceinline__ int sig32(int g, int j) {
    return 16 * (j >> 2) + 4 * g + (j & 3);
}

#define MFMA32(a,b,c) __builtin_amdgcn_mfma_f32_16x16x32_bf16(a, b, c, 0, 0, 0)
#define MFMA16(a,b,c) __builtin_amdgcn_mfma_f32_16x16x16bf16_1k(a, b, c, 0, 0, 0)

// e-frag bundle: the 12 row-scale values one lane needs for one step.
struct E3 { f4 a, b, c; };
__device__ __forceinline__ E3 lde(const float* __restrict__ p) {
    E3 e;
    e.a = *(const f4*)(p);          // e[4g + 0..3]      (m-tile 0 rows)
    e.b = *(const f4*)(p + 16);     // e[16 + 4g + 0..3] (m-tile 1)
    e.c = *(const f4*)(p + 32);     // e[32 + 4g + 0..3] (m-tile 2)
    return e;
}

// ---------------------------------------------------------------------------
// One scan step (round-0 proven math): per n-tile, D = A32*B32 (rows 0..31)
// + A16*B16 (rows 32..47), rowscale by e, repack. e passed in REGISTERS so
// the ds_read can be software-pipelined by the caller.
// ---------------------------------------------------------------------------
__device__ __forceinline__ void scan_step_e(const bf16x8 (&A32)[3], const s4h (&A16)[3],
                                            bf16x8 (&B32)[3], s4h (&B16)[3],
                                            const E3& e)
{
    const f4 z = {0.f, 0.f, 0.f, 0.f};
#pragma unroll
    for (int nt = 0; nt < 3; ++nt) {
        f4 c0v = MFMA32(A32[0], B32[nt], z);
        f4 c1v = MFMA32(A32[1], B32[nt], z);
        f4 c2v = MFMA32(A32[2], B32[nt], z);
        c0v = MFMA16(A16[0], B16[nt], c0v);
        c1v = MFMA16(A16[1], B16[nt], c1v);
        c2v = MFMA16(A16[2], B16[nt], c2v);
        U32x4 nb;
        nb.u[0] = pk_trunc(c0v[0] * e.a[0], c0v[1] * e.a[1]);
        nb.u[1] = pk_trunc(c0v[2] * e.a[2], c0v[3] * e.a[3]);
        nb.u[2] = pk_trunc(c1v[0] * e.b[0], c1v[1] * e.b[1]);
        nb.u[3] = pk_trunc(c1v[2] * e.b[2], c1v[3] * e.b[3]);
        B32[nt] = nb.v;
        U32x2 nc;
        nc.u[0] = pk_trunc(c2v[0] * e.c[0], c2v[1] * e.c[1]);
        nc.u[1] = pk_trunc(c2v[2] * e.c[2], c2v[3] * e.c[3]);
        B16[nt] = nc.v;
    }
}

__device__ __forceinline__ void scan_step(const bf16x8 (&A32)[3], const s4h (&A16)[3],
                                          bf16x8 (&B32)[3], s4h (&B16)[3],
                                          const float* __restrict__ eb)
{
    scan_step_e(A32, A16, B32, B16, lde(eb));
}

// ---------------------------------------------------------------------------
// Phase 1: one wave per (batch, chunk): 48x48 transfer-matrix product in regs.
// 768 blocks x 4 waves = 3072 waves = 256 batches x 12 chunks (3 blocks/CU).
// NEW vs round 0: the 16-step inner block register-prefetches the e-frags
// 2 steps ahead (static double-buffer), so each ds_read_b128 retires under
// ~2 steps of MFMA+VALU instead of stalling the repack muls.
// ---------------------------------------------------------------------------
__global__ __launch_bounds__(256, 3)
void crf_scan(const float* __restrict__ em, const float* __restrict__ trn,
              float* __restrict__ pws, float* __restrict__ outz)
{
    __shared__ float lex[4][16 * Tt];          // per-wave 16-step exp(em) buffer
    const int tid = threadIdx.x, wv = tid >> 6, l = tid & 63;
    const int c0 = l & 15, g = l >> 4;
    const int wid = blockIdx.x * 4 + wv;
    const int b = wid / NCK, ck = wid % NCK;
    if (blockIdx.x == 0 && tid == 0) outz[0] = 0.0f;   // zero d_out for finish

    // A-frags: A32[mt] slot (g,j) = exp(trn[sig32(g,j)][16mt+c0])
    bf16x8 A32[3]; s4h A16[3];
#pragma unroll
    for (int mt = 0; mt < 3; ++mt) {
        float v[8];
#pragma unroll
        for (int j = 0; j < 8; ++j)
            v[j] = __expf(trn[sig32(g, j) * Tt + 16 * mt + c0]);
        U32x4 a;
        a.u[0] = pk_rne(v[0], v[1]); a.u[1] = pk_rne(v[2], v[3]);
        a.u[2] = pk_rne(v[4], v[5]); a.u[3] = pk_rne(v[6], v[7]);
        A32[mt] = a.v;
        float w0 = __expf(trn[(32 + 4 * g + 0) * Tt + 16 * mt + c0]);
        float w1 = __expf(trn[(32 + 4 * g + 1) * Tt + 16 * mt + c0]);
        float w2 = __expf(trn[(32 + 4 * g + 2) * Tt + 16 * mt + c0]);
        float w3 = __expf(trn[(32 + 4 * g + 3) * Tt + 16 * mt + c0]);
        U32x2 c;
        c.u[0] = pk_rne(w0, w1); c.u[1] = pk_rne(w2, w3);
        A16[mt] = c.v;
    }

    // State init = identity
    bf16x8 B32[3]; s4h B16[3];
#pragma unroll
    for (int nt = 0; nt < 3; ++nt) {
        U32x4 bi;
#pragma unroll
        for (int q = 0; q < 4; ++q) {
            unsigned lo = (sig32(g, 2 * q)     == 16 * nt + c0) ? 0x3F80u : 0u;
            unsigned hi = (sig32(g, 2 * q + 1) == 16 * nt + c0) ? 0x3F80u : 0u;
            bi.u[q] = lo | (hi << 16);
        }
        B32[nt] = bi.v;
        U32x2 ci;
#pragma unroll
        for (int q = 0; q < 2; ++q) {
            unsigned lo = (nt == 2 && 4 * g + 2 * q     == c0) ? 0x3F80u : 0u;
            unsigned hi = (nt == 2 && 4 * g + 2 * q + 1 == c0) ? 0x3F80u : 0u;
            ci.u[q] = lo | (hi << 16);
        }
        B16[nt] = ci.v;
    }

    const int total = (ck == NCK - 1) ? (Ss - 1 - ck * CLEN) : CLEN;  // 171 / 166
    const int s0 = ck * CLEN + 1;
    const float* emb = em + (size_t)b * (Ss * Tt);
    float* lw = &lex[wv][0];
    const float* lexg = lw + g * 4;
    const long lim = (long)Ss * Tt - 4;

    // prefetch sub 0 (early-issued global loads, consumed at loop top)
    f4 r[3];
#pragma unroll
    for (int i = 0; i < 3; ++i) {
        long o = (long)s0 * Tt + l * 4 + i * 256;
        if (o > lim) o = lim;
        r[i] = *(const f4*)(emb + o);
    }

    const int nsub = (total + 15) >> 4;
    for (int sub = 0; sub < nsub; ++sub) {
#pragma unroll
        for (int i = 0; i < 3; ++i)
#pragma unroll
            for (int j = 0; j < 4; ++j) r[i][j] = __expf(r[i][j] - C_SHIFT);
#pragma unroll
        for (int i = 0; i < 3; ++i) *(f4*)(lw + l * 4 + i * 256) = r[i];

        if (sub + 1 < nsub) {        // issue next sub's loads before compute
#pragma unroll
            for (int i = 0; i < 3; ++i) {
                long o = (long)(s0 + (sub + 1) * 16) * Tt + l * 4 + i * 256;
                if (o > lim) o = lim;
                r[i] = *(const f4*)(emb + o);
            }
        }

        int nsteps = total - sub * 16;
        if (nsteps >= 16) {
            // register-pipelined e-frags, 2 steps deep (static dbuf; indices
            // fold at compile time under full unroll -> stays in VGPRs)
            E3 eb0 = lde(lexg + 0 * Tt);
            E3 eb1 = lde(lexg + 1 * Tt);
#pragma unroll
            for (int u = 0; u < 16; ++u) {
                E3 cur = (u & 1) ? eb1 : eb0;
                if (u + 2 < 16) {
                    if (u & 1) eb1 = lde(lexg + (u + 2) * Tt);
                    else       eb0 = lde(lexg + (u + 2) * Tt);
                }
                scan_step_e(A32, A16, B32, B16, cur);
            }
        } else {
            for (int u = 0; u < nsteps; ++u)
                scan_step(A32, A16, B32, B16, lexg + u * Tt);
        }
    }

    // store 18 u32/lane, coalesced
    unsigned* pw = (unsigned*)pws + (size_t)wid * 1152 + l;
#pragma unroll
    for (int nt = 0; nt < 3; ++nt) {
        U32x4 a; a.v = B32[nt];
        U32x2 c; c.v = B16[nt];
        pw[(nt * 6 + 0) * 64] = a.u[0];
        pw[(nt * 6 + 1) * 64] = a.u[1];
        pw[(nt * 6 + 2) * 64] = a.u[2];
        pw[(nt * 6 + 3) * 64] = a.u[3];
        pw[(nt * 6 + 4) * 64] = c.u[0];
        pw[(nt * 6 + 5) * 64] = c.u[1];
    }
}

// ---------------------------------------------------------------------------
// Phase 2 + gold, merged: one block per batch; wave 0 chains the 12 chunk
// matrices with renorm, combines with gold. (Round-0 proven version.)
// ---------------------------------------------------------------------------
__global__ __launch_bounds__(256)
void crf_finish(const float* __restrict__ em, const int* __restrict__ tags,
                const int* __restrict__ mask, const float* __restrict__ trn,
                const float* __restrict__ stt, const float* __restrict__ ent,
                const float* __restrict__ pws, float* __restrict__ out)
{
    __shared__ float red[256];
    __shared__ float alpha[Tt];
    const int b = blockIdx.x, t = threadIdx.x;

    // gold partial
    const int* tg = tags + (size_t)b * Ss;
    float local = 0.0f;
    for (int s = t; s < Ss; s += 256) {
        if (s > 0) {
            int pv = tg[s - 1], cu = tg[s];
            float mf = (float)mask[(size_t)b * Ss + s];
            local += (trn[pv * Tt + cu] + em[((size_t)b * Ss + s) * Tt + cu]) * mf;
        }
    }
    if (t == 0) {
        int t0 = tg[0];
        local += stt[t0] + em[(size_t)b * Ss * Tt + t0];
        local += ent[tg[Ss - 1]];
    }
    red[t] = local;
    __syncthreads();
    if (t < 128) red[t] += red[t + 128];
    __syncthreads();

    if (t < 64) {
        const int l = t, c0 = l & 15, g = l >> 4;
        float gsum = red[l] + red[l + 64];
#pragma unroll
        for (int m = 32; m >= 1; m >>= 1) gsum += __shfl_xor(gsum, m);

        if (l < Tt) alpha[l] = __expf(stt[l] + em[(size_t)b * Ss * Tt + l] - C_SHIFT);

        float acc = 0.0f;
        const unsigned* pw = (const unsigned*)pws + (size_t)b * NCK * 1152 + l;
        for (int ck = 0; ck < NCK; ++ck) {
            float y[12];
#pragma unroll
            for (int i = 0; i < 12; ++i) y[i] = 0.0f;
#pragma unroll
            for (int nt = 0; nt < 3; ++nt) {
                float av = alpha[16 * nt + c0];
                unsigned w[6];
#pragma unroll
                for (int q = 0; q < 6; ++q) w[q] = pw[(size_t)ck * 1152 + (nt * 6 + q) * 64];
#pragma unroll
                for (int q = 0; q < 6; ++q) {
                    y[2 * q]     += bfu(w[q] << 16)         * av;
                    y[2 * q + 1] += bfu(w[q] & 0xFFFF0000u) * av;
                }
            }
#pragma unroll
            for (int m = 1; m <= 8; m <<= 1)
#pragma unroll
                for (int i = 0; i < 12; ++i) y[i] += __shfl_xor(y[i], m);
            float mx = y[0];
#pragma unroll
            for (int i = 1; i < 12; ++i) mx = fmaxf(mx, y[i]);
            mx = fmaxf(mx, __shfl_xor(mx, 16));
            mx = fmaxf(mx, __shfl_xor(mx, 32));
            acc += __logf(mx);
            float rm = 1.0f / mx;
            if (c0 == 0) {
#pragma unroll
                for (int tt = 0; tt < 3; ++tt)
#pragma unroll
                    for (int rr = 0; rr < 4; ++rr)
                        alpha[16 * tt + 4 * g + rr] = y[4 * tt + rr] * rm;
            }
        }
        // fwd = log(sum alpha * exp(ent)) + acc + S*C
        float part = (l < Tt) ? alpha[l] * __expf(ent[l]) : 0.0f;
#pragma unroll
        for (int m = 32; m >= 1; m >>= 1) part += __shfl_xor(part, m);
        if (t == 0) {
            float fwd = __logf(part) + acc + (float)Ss * C_SHIFT;
            atomicAdd(out, (fwd - gsum) * (1.0f / 256.0f));
        }
    }
}

// ---------------------------------------------------------------------------
extern "C" void kernel_launch(void* const* d_in, const int* in_sizes, int n_in,
                              void* d_out, int out_size, void* d_ws, size_t ws_size,
                              hipStream_t stream)
{
    const float* em  = (const float*)d_in[0];
    const int* tags  = (const int*)d_in[1];
    const int* mask  = (const int*)d_in[2];
    const float* trn = (const float*)d_in[3];
    const float* stt = (const float*)d_in[4];
    const float* ent = (const float*)d_in[5];
    float* out = (float*)d_out;
    float* pws = (float*)d_ws;   // 3072 waves x 1152 u32 = 14.16 MB (proven safe)

    crf_scan<<<768, 256, 0, stream>>>(em, trn, pws, out);
    crf_finish<<<256, 256, 0, stream>>>(em, tags, mask, trn, stt, ent, pws, out);
}